// Round 18
// baseline (112.271 us; speedup 1.0000x reference)
//
#include <hip/hip_runtime.h>
#include <stdint.h>
#include <stddef.h>

// ---------------------------------------------------------------------------
// Fused transformer attention block for MI355X (gfx950)
//   x[2,2048,1024] fp32 -> QKV proj(+RoPE fused) -> 16-head softmax attn -> out proj
// bf16 MFMA (16x16x32), fp32 accumulate.
// R18: XCD n-BANDING in both GEMMs: each XCD owns nx/8 n-tiles (B working
//      set 768KB/256KB -> L2-resident; A streams). Old mapping streamed the
//      full 6MB B through every XCD's 4MB L2 (~190MB L3 re-fetch = the
//      schedule-invariant 46us). Everything else frozen (R17).
// ---------------------------------------------------------------------------

typedef short          bf16x8 __attribute__((ext_vector_type(8)));
typedef float          f32x4  __attribute__((ext_vector_type(4)));
typedef unsigned short u16x4  __attribute__((ext_vector_type(4)));
typedef unsigned short u16x8  __attribute__((ext_vector_type(8)));

#define B_   2
#define L_   2048
#define D_   1024
#define H_   16
#define HD_  64
#define BL_  4096           // B_*L_
#define LOG2E 1.4426950408889634f
#define QSC  0.18033688011112042f   // 0.125 * LOG2E (scale+log2e folded into Q)

__device__ __forceinline__ unsigned short f2bf(float f) {   // RNE f32->bf16
  unsigned int u = __float_as_uint(f);
  u += 0x7FFFu + ((u >> 16) & 1u);
  return (unsigned short)(u >> 16);
}
__device__ __forceinline__ float bf2f(unsigned short h) {
  return __uint_as_float(((unsigned int)h) << 16);
}
__device__ __forceinline__ uint32_t cvtpk_bf16(float lo, float hi) {
  uint32_t r;
  asm("v_cvt_pk_bf16_f32 %0, %1, %2" : "=v"(r) : "v"(lo), "v"(hi));
  return r;
}
// raw v_exp_f32: D = 2^S0 (~1 ulp; inputs here are |x| < ~40, no edge cases)
__device__ __forceinline__ float fast_exp2(float x) {
  float r;
  asm("v_exp_f32 %0, %1" : "=v"(r) : "v"(x));
  return r;
}

// async global->LDS, 16B per lane; LDS dest is wave-uniform base + lane*16
__device__ __forceinline__ void gload_lds16(const unsigned short* g, unsigned short* l) {
  __builtin_amdgcn_global_load_lds(
      (__attribute__((address_space(1))) void*)g,
      (__attribute__((address_space(3))) void*)l, 16, 0, 0);
}

// ---------------------------------------------------------------------------
// Fused preprocessing (frozen): one kernel, range-partitioned grid.
// ---------------------------------------------------------------------------
__device__ __forceinline__ void transpose_tile(
    const float* __restrict__ src, unsigned short* __restrict__ dst,
    int K, int N, int n0, int k0, int tid, float (*tile)[33]) {
  const int tx = tid & 31, ty = tid >> 5;   // (32,8)
#pragma unroll
  for (int i = 0; i < 4; ++i)
    tile[ty * 4 + i][tx] = src[(size_t)(k0 + ty * 4 + i) * N + n0 + tx];
  __syncthreads();
#pragma unroll
  for (int i = 0; i < 4; ++i)
    dst[(size_t)(n0 + ty * 4 + i) * K + k0 + tx] = f2bf(tile[tx][ty * 4 + i]);
}

__global__ void __launch_bounds__(256)
prep_kernel(const float* __restrict__ x,
            const float* __restrict__ Wqkv,
            const float* __restrict__ Wout,
            u16x8* __restrict__ xb,
            unsigned short* __restrict__ WqkvT,
            unsigned short* __restrict__ WoutT,
            float2* __restrict__ rtbl) {
  __shared__ float tile[32][33];
  const int bid = blockIdx.x, tid = threadIdx.x;
  if (bid < 2048) {                       // cast x -> bf16
    const int i = bid * 256 + tid;        // 524288 total, exact
    const float4 a = ((const float4*)x)[2 * i];
    const float4 b = ((const float4*)x)[2 * i + 1];
    u16x8 o;
    o[0] = f2bf(a.x); o[1] = f2bf(a.y); o[2] = f2bf(a.z); o[3] = f2bf(a.w);
    o[4] = f2bf(b.x); o[5] = f2bf(b.y); o[6] = f2bf(b.z); o[7] = f2bf(b.w);
    xb[i] = o;
  } else if (bid < 2304) {                // RoPE table
    const int i = (bid - 2048) * 256 + tid;   // 65536
    const int pos = i >> 5, j = i & 31;
    const float inv = exp2f(-(float)j * 0.4152410118609203f);   // log2(1e4)/32
    float s, c;
    sincosf((float)pos * inv, &s, &c);
    rtbl[i] = make_float2(c, s);
  } else if (bid < 5376) {                // Wqkv transpose
    const int t = bid - 2304;             // 96 x 32
    transpose_tile(Wqkv, WqkvT, D_, 3 * D_, (t % 96) * 32, (t / 96) * 32, tid, tile);
  } else {                                // Wout transpose
    const int t = bid - 5376;             // 32 x 32
    transpose_tile(Wout, WoutT, D_, D_, (t % 32) * 32, (t / 32) * 32, tid, tile);
  }
}

// ---------------------------------------------------------------------------
// gemm_bt3 (R16 loop + R17 epilogue + R18 XCD n-banding): C = A * Bt^T + bias.
// 128x128 tile, BK=64, 4 waves (2x2, 64x64 out each). Rows = 128B ->
// (row&7)<<4 XOR swizzle (0 conflicts measured). LDS 64KB -> 2 blocks/CU.
// Grid mapping: xcd = bid&7 owns n-tiles [xcd*nband, (xcd+1)*nband),
// m-major within the band -> B-panel working set nband*256KB L2-resident.
// MODE 0 epilogue: per-wave LDS staging tile, coalesced u16x8 write-out.
// MODE 1: fp32 out + bias.
// ---------------------------------------------------------------------------
template <int MODE>
__global__ void __launch_bounds__(256)
gemm_bt3(const unsigned short* __restrict__ A,
         const unsigned short* __restrict__ Bt,
         const float* __restrict__ bias,
         const float2* __restrict__ rt,
         float* __restrict__ outF,
         unsigned short* __restrict__ Qb,
         unsigned short* __restrict__ Kb,
         unsigned short* __restrict__ Vt,
         int M, int N, int K) {
  __shared__ unsigned short As[2][8192];   // [buf][128 rows][64 k] bf16, swz
  __shared__ unsigned short Bs[2][8192];
  const int tid = threadIdx.x;
  const int w = tid >> 6, l = tid & 63;
  const int lg = l >> 4, ll = l & 15;
  // R18: XCD n-banding (nx % 8 == 0). xcd owns n-band; m-major inside.
  const int nx = N >> 7;
  const int nband = nx >> 3;
  const int xcd = blockIdx.x & 7;
  const int idx = blockIdx.x >> 3;
  const int n0 = (xcd * nband + idx % nband) * 128;
  const int m0 = (idx / nband) * 128;
  const int wm = (w >> 1) * 64, wn = (w & 1) * 64;

  f32x4 acc[4][4] = {};

  // staging: slot idx = c*256 + tid -> row = idx>>3 (0..127), slot = idx&7;
  // source col pre-swizzled (slot ^ (row&7)) so linear-LDS + XOR-read works.
  int srcOff[4];
#pragma unroll
  for (int c = 0; c < 4; ++c) {
    const int sidx = c * 256 + tid;
    const int row = sidx >> 3, slot = sidx & 7;
    srcOff[c] = row * K + ((slot ^ (row & 7)) << 3);   // ushort offset
  }
  const unsigned short* gA = A + (size_t)m0 * K;
  const unsigned short* gB = Bt + (size_t)n0 * K;

  auto stage = [&](int bsel, int kt) {
    const int kk = kt * 64;
#pragma unroll
    for (int c = 0; c < 4; ++c)
      gload_lds16(gA + srcOff[c] + kk, &As[bsel][c * 2048 + w * 512]);
#pragma unroll
    for (int c = 0; c < 4; ++c)
      gload_lds16(gB + srcOff[c] + kk, &Bs[bsel][c * 2048 + w * 512]);
  };

  const int NT = K >> 6;                   // 16
  int buf = 0;

  stage(0, 0);
  for (int kt = 0; kt < NT; ++kt) {
    __syncthreads();                      // drains vmcnt -> staged tile visible
    if (kt + 1 < NT) stage(buf ^ 1, kt + 1);
    const char* pa = (const char*)&As[buf][0];
    const char* pb = (const char*)&Bs[buf][0];
#pragma unroll
    for (int kk = 0; kk < 2; ++kk) {
      bf16x8 af[4], bfv[4];
#pragma unroll
      for (int mi = 0; mi < 4; ++mi) {
        const int row = wm + mi * 16 + ll;
        af[mi] = *(const bf16x8*)(pa + row * 128 +
                                  ((kk * 64 + lg * 16) ^ ((row & 7) << 4)));
      }
#pragma unroll
      for (int ni = 0; ni < 4; ++ni) {
        const int row = wn + ni * 16 + ll;
        bfv[ni] = *(const bf16x8*)(pb + row * 128 +
                                   ((kk * 64 + lg * 16) ^ ((row & 7) << 4)));
      }
      __builtin_amdgcn_s_setprio(1);
#pragma unroll
      for (int mi = 0; mi < 4; ++mi)
#pragma unroll
        for (int ni = 0; ni < 4; ++ni)
          acc[mi][ni] = __builtin_amdgcn_mfma_f32_16x16x32_bf16(
              af[mi], bfv[ni], acc[mi][ni], 0, 0, 0);
      __builtin_amdgcn_s_setprio(0);
    }
    buf ^= 1;
  }

  // epilogue. C layout: row = (l>>4)*4 + reg, col = l&15   (guide m89/m91)
  if (MODE == 0) {
    __syncthreads();                      // all waves done reading As/Bs
    // per-wave staging tile: 64 x 72 u16 (pitch 144B, 16B-aligned rows)
    unsigned short* et = (w < 2 ? &As[0][0] : &Bs[0][0]) + (w & 1) * 4608;
    const int t  = (n0 + wn) >> 10;       // 0=q 1=k 2=v, wave-uniform
    const int bb = (m0 + wm) >> 11;       // batch (wave-uniform)
    const int P0 = (m0 + wm) & 2047;      // 64-aligned pos window base
    const int h  = ((n0 + wn) & 1023) >> 6;
    const int bh = bb * H_ + h;
    if (t == 2) {                         // V: sigma at LDS-write, et[d][posS]
#pragma unroll
      for (int ni = 0; ni < 4; ++ni) {
        const int d = ni * 16 + ll;
        const float bv = bias[n0 + wn + ni * 16 + ll];
#pragma unroll
        for (int mi = 0; mi < 4; ++mi) {
          const int row0 = mi * 16 + lg * 4;        // local pos, 4-aligned
          const int wb = (row0 >> 2) & 7;
          const int posS = (row0 & ~31) + 8 * (wb & 3) + 4 * (wb >> 2);
#pragma unroll
          for (int rg = 0; rg < 4; ++rg)
            et[d * 72 + posS + rg] = f2bf(acc[mi][ni][rg] + bv);
        }
      }
      // same-wave write->read (compiler orders LDS deps); coalesced out
      unsigned short* gbase = Vt + (size_t)bh * HD_ * L_ + P0;
#pragma unroll
      for (int pass = 0; pass < 8; ++pass) {
        const int d = pass * 8 + (l >> 3);
        const int slot = l & 7;
        const u16x8 v = *(const u16x8*)(et + d * 72 + slot * 8);
        *(u16x8*)(gbase + (size_t)d * L_ + slot * 8) = v;
      }
    } else {                              // Q/K: RoPE in-register -> et[row][d]
      unsigned short* dst = (t == 0) ? Qb : Kb;
      const float qsc = (t == 0) ? QSC : 1.0f;
#pragma unroll
      for (int ni = 0; ni < 2; ++ni) {
        const int d = ni * 16 + ll;       // 0..31
        const float bv1 = bias[n0 + wn + ni * 16 + ll];
        const float bv2 = bias[n0 + wn + (ni + 2) * 16 + ll];
#pragma unroll
        for (int mi = 0; mi < 4; ++mi) {
#pragma unroll
          for (int rg = 0; rg < 4; ++rg) {
            const int row = mi * 16 + lg * 4 + rg;  // local pos
            const float2 cs = rt[(P0 + row) * 32 + d];
            const float q1 = acc[mi][ni][rg] + bv1;
            const float q2 = acc[mi][ni + 2][rg] + bv2;
            et[row * 72 + d]      = f2bf((q1 * cs.x - q2 * cs.y) * qsc);
            et[row * 72 + d + 32] = f2bf((q2 * cs.x + q1 * cs.y) * qsc);
          }
        }
      }
      unsigned short* gbase = dst + ((size_t)bh * L_ + P0) * HD_;
#pragma unroll
      for (int pass = 0; pass < 8; ++pass) {
        const int row = pass * 8 + (l >> 3);
        const int slot = l & 7;
        const u16x8 v = *(const u16x8*)(et + row * 72 + slot * 8);
        *(u16x8*)(gbase + (size_t)row * HD_ + slot * 8) = v;
      }
    }
  } else {
#pragma unroll
    for (int ni = 0; ni < 4; ++ni) {
      const int n = n0 + wn + ni * 16 + ll;
      const float bv = bias[n];
#pragma unroll
      for (int mi = 0; mi < 4; ++mi) {
        const int row0 = m0 + wm + mi * 16 + lg * 4;
#pragma unroll
        for (int rg = 0; rg < 4; ++rg)
          outF[(size_t)(row0 + rg) * N + n] = acc[mi][ni][rg] + bv;
      }
    }
  }
}

// ---------------------------------------------------------------------------
// Flash attention (R13, frozen): 8 waves x 16 q-rows; KVBLK=128 as 2x[64][64]
// chunks; swapped QK^T; in-register P; sigma-permuted Vt; no-max softmax;
// raw v_exp_f32; row sum via osum = mfma(pa, ones).
// ---------------------------------------------------------------------------
__global__ void __launch_bounds__(512)
attn_kernel(const unsigned short* __restrict__ Qb,
            const unsigned short* __restrict__ Kb,
            const unsigned short* __restrict__ Vt,
            unsigned short* __restrict__ Ob) {
  __shared__ unsigned short Ks[2][2][4096];  // [buf][kc][kv 64][d 64], swizzled
  __shared__ unsigned short Vs[2][2][4096];  // [buf][kc][d 64][kv' 64], swizzled
  const int tid = threadIdx.x, w = tid >> 6, l = tid & 63;
  const int lg = l >> 4, ll = l & 15;
  const int bid = ((blockIdx.x & 7) << 6) + (blockIdx.x >> 3);
  const int bh  = bid >> 4;
  const int q0  = (bid & 15) * 128;
  const unsigned short* Qp = Qb + ((size_t)bh * L_ + q0 + w * 16) * HD_;
  const unsigned short* Kp = Kb + (size_t)bh * L_ * HD_;
  const unsigned short* Vp = Vt + (size_t)bh * HD_ * L_;

  const int srow = tid >> 3;
  const int scol = ((tid & 7) ^ (srow & 7)) * 8;
  auto stage = [&](int bsel, int kv0) {
#pragma unroll
    for (int c = 0; c < 2; ++c) {
      gload_lds16(Kp + (size_t)(kv0 + c * 64 + srow) * HD_ + scol, &Ks[bsel][c][w * 512]);
      gload_lds16(Vp + (size_t)srow * L_ + kv0 + c * 64 + scol, &Vs[bsel][c][w * 512]);
    }
  };

  bf16x8 qf[2];
#pragma unroll
  for (int ks = 0; ks < 2; ++ks)
    qf[ks] = *(const bf16x8*)(Qp + (size_t)ll * HD_ + ks * 32 + 8 * lg);

  bf16x8 ones;
#pragma unroll
  for (int j = 0; j < 8; ++j) ones[j] = (short)0x3F80;

  f32x4 o[4] = {};
  f32x4 osum = {};                           // row-sum acc: osum[rg] for q=lg*4+rg

  stage(0, 0);
  __syncthreads();

  int buf = 0;
  for (int t = 0; t < 16; ++t) {
    if (t + 1 < 16) stage(buf ^ 1, (t + 1) * 128);
    f32x4 s[2][4];

#pragma unroll
    for (int kc = 0; kc < 2; ++kc) {
      const char* Ksb = (const char*)&Ks[buf][kc][0];
      bf16x8 kfr[4][2];
#pragma unroll
      for (int ni = 0; ni < 4; ++ni)
#pragma unroll
        for (int ks = 0; ks < 2; ++ks)
          kfr[ni][ks] = *(const bf16x8*)(Ksb + (ni * 16 + ll) * 128 +
                                         ((ks * 64 + lg * 16) ^ ((ll & 7) << 4)));
#pragma unroll
      for (int ni = 0; ni < 4; ++ni) s[kc][ni] = f32x4{0.f, 0.f, 0.f, 0.f};
      __builtin_amdgcn_s_setprio(1);
#pragma unroll
      for (int ks = 0; ks < 2; ++ks)
#pragma unroll
        for (int ni = 0; ni < 4; ++ni)
          s[kc][ni] = __builtin_amdgcn_mfma_f32_16x16x32_bf16(kfr[ni][ks], qf[ks], s[kc][ni], 0, 0, 0);
      __builtin_amdgcn_s_setprio(0);
    }

    bf16x8 pa[2][2];                       // [kc][ks]
#pragma unroll
    for (int kc = 0; kc < 2; ++kc) {
      uint32_t wd[4][2];
#pragma unroll
      for (int ni = 0; ni < 4; ++ni) {
        const float p0 = fast_exp2(s[kc][ni][0]);
        const float p1 = fast_exp2(s[kc][ni][1]);
        const float p2 = fast_exp2(s[kc][ni][2]);
        const float p3 = fast_exp2(s[kc][ni][3]);
        wd[ni][0] = cvtpk_bf16(p0, p1);
        wd[ni][1] = cvtpk_bf16(p2, p3);
      }
#pragma unroll
      for (int ks = 0; ks < 2; ++ks) {
        union { uint32_t u[4]; bf16x8 v; } pu;
        pu.u[0] = wd[2 * ks][0];     pu.u[1] = wd[2 * ks][1];
        pu.u[2] = wd[2 * ks + 1][0]; pu.u[3] = wd[2 * ks + 1][1];
        pa[kc][ks] = pu.v;
      }
    }

#pragma unroll
    for (int kc = 0; kc < 2; ++kc) {
      const char* Vsb = (const char*)&Vs[buf][kc][0];
      bf16x8 vf[2][4];
#pragma unroll
      for (int ks = 0; ks < 2; ++ks)
#pragma unroll
        for (int ni = 0; ni < 4; ++ni)
          vf[ks][ni] = *(const bf16x8*)(Vsb + (ni * 16 + ll) * 128 +
                                        ((ks * 64 + lg * 16) ^ ((ll & 7) << 4)));
      __builtin_amdgcn_s_setprio(1);
#pragma unroll
      for (int ks = 0; ks < 2; ++ks) {
#pragma unroll
        for (int ni = 0; ni < 4; ++ni)
          o[ni] = __builtin_amdgcn_mfma_f32_16x16x32_bf16(pa[kc][ks], vf[ks][ni], o[ni], 0, 0, 0);
        osum = __builtin_amdgcn_mfma_f32_16x16x32_bf16(pa[kc][ks], ones, osum, 0, 0, 0);
      }
      __builtin_amdgcn_s_setprio(0);
    }

    __syncthreads();
    buf ^= 1;
  }

  const int b = bh >> 4, h = bh & 15;
  unsigned short* Op = Ob + ((size_t)b * L_ + q0 + w * 16) * D_ + h * HD_;
#pragma unroll
  for (int rg = 0; rg < 4; ++rg) {
    const float iq = 1.0f / osum[rg];
#pragma unroll
    for (int ni = 0; ni < 4; ++ni)
      Op[(size_t)(lg * 4 + rg) * D_ + ni * 16 + ll] = f2bf(o[ni][rg] * iq);
  }
}

// ---------------------------------------------------------------------------
extern "C" void kernel_launch(void* const* d_in, const int* in_sizes, int n_in,
                              void* d_out, int out_size, void* d_ws, size_t ws_size,
                              hipStream_t stream) {
  const float* x    = (const float*)d_in[0];
  const float* Wqkv = (const float*)d_in[1];
  const float* bqkv = (const float*)d_in[2];
  const float* Wout = (const float*)d_in[3];
  const float* bout = (const float*)d_in[4];
  float* out = (float*)d_out;

  char* ws = (char*)d_ws;                       // 48 MiB used
  unsigned short* xb    = (unsigned short*)(ws);                    // 8 MiB
  unsigned short* WqkvT = (unsigned short*)(ws + (8ull  << 20));    // 6 MiB
  unsigned short* WoutT = (unsigned short*)(ws + (14ull << 20));    // 2 MiB
  unsigned short* Qb    = (unsigned short*)(ws + (16ull << 20));    // 8 MiB
  unsigned short* Kb    = (unsigned short*)(ws + (24ull << 20));    // 8 MiB
  unsigned short* Vt    = (unsigned short*)(ws + (32ull << 20));    // 8 MiB
  unsigned short* Ob    = (unsigned short*)(ws + (40ull << 20));    // 8 MiB
  float2* rtbl = (float2*)(ws + (40ull << 20));  // aliases Ob (dead by attn)

  prep_kernel<<<6400, 256, 0, stream>>>(x, Wqkv, Wout, (u16x8*)xb, WqkvT, WoutT, rtbl);

  gemm_bt3<0><<<(3 * D_ / 128) * (BL_ / 128), 256, 0, stream>>>(
      xb, WqkvT, bqkv, rtbl, nullptr, Qb, Kb, Vt, BL_, 3 * D_, D_);

  attn_kernel<<<B_ * H_ * (L_ / 128), 512, 0, stream>>>(Qb, Kb, Vt, Ob);

  gemm_bt3<1><<<(D_ / 128) * (BL_ / 128), 256, 0, stream>>>(
      Ob, WoutT, bout, nullptr, out, nullptr, nullptr, nullptr, BL_, D_, D_);
}

// Round 19
// 106.981 us; speedup vs baseline: 1.0495x; 1.0495x over previous
//
#include <hip/hip_runtime.h>
#include <stdint.h>
#include <stddef.h>

// ---------------------------------------------------------------------------
// Fused transformer attention block for MI355X (gfx950)
//   x[2,2048,1024] fp32 -> QKV proj(+RoPE fused) -> 16-head softmax attn -> out proj
// bf16 MFMA (16x16x32), fp32 accumulate.
// R19: GEMMs -> 8 waves (512 thr), 4M x 2N wave grid, 32x64 out/wave.
//      Same 128^2/BK=64 tile + swizzle + staging; LDS 64KB -> 2 blocks/CU
//      -> 4 waves/SIMD (was 2). Five schedule/locality theories converged
//      at 46us with nothing saturated => latency-bound, TLP never tested.
//      attn (R13), prep, XCD banding (R18) frozen.
// ---------------------------------------------------------------------------

typedef short          bf16x8 __attribute__((ext_vector_type(8)));
typedef float          f32x4  __attribute__((ext_vector_type(4)));
typedef unsigned short u16x4  __attribute__((ext_vector_type(4)));
typedef unsigned short u16x8  __attribute__((ext_vector_type(8)));

#define B_   2
#define L_   2048
#define D_   1024
#define H_   16
#define HD_  64
#define BL_  4096           // B_*L_
#define LOG2E 1.4426950408889634f
#define QSC  0.18033688011112042f   // 0.125 * LOG2E (scale+log2e folded into Q)

__device__ __forceinline__ unsigned short f2bf(float f) {   // RNE f32->bf16
  unsigned int u = __float_as_uint(f);
  u += 0x7FFFu + ((u >> 16) & 1u);
  return (unsigned short)(u >> 16);
}
__device__ __forceinline__ float bf2f(unsigned short h) {
  return __uint_as_float(((unsigned int)h) << 16);
}
__device__ __forceinline__ uint32_t cvtpk_bf16(float lo, float hi) {
  uint32_t r;
  asm("v_cvt_pk_bf16_f32 %0, %1, %2" : "=v"(r) : "v"(lo), "v"(hi));
  return r;
}
// raw v_exp_f32: D = 2^S0 (~1 ulp; inputs here are |x| < ~40, no edge cases)
__device__ __forceinline__ float fast_exp2(float x) {
  float r;
  asm("v_exp_f32 %0, %1" : "=v"(r) : "v"(x));
  return r;
}

// async global->LDS, 16B per lane; LDS dest is wave-uniform base + lane*16
__device__ __forceinline__ void gload_lds16(const unsigned short* g, unsigned short* l) {
  __builtin_amdgcn_global_load_lds(
      (__attribute__((address_space(1))) void*)g,
      (__attribute__((address_space(3))) void*)l, 16, 0, 0);
}

// ---------------------------------------------------------------------------
// Fused preprocessing (frozen): one kernel, range-partitioned grid.
// ---------------------------------------------------------------------------
__device__ __forceinline__ void transpose_tile(
    const float* __restrict__ src, unsigned short* __restrict__ dst,
    int K, int N, int n0, int k0, int tid, float (*tile)[33]) {
  const int tx = tid & 31, ty = tid >> 5;   // (32,8)
#pragma unroll
  for (int i = 0; i < 4; ++i)
    tile[ty * 4 + i][tx] = src[(size_t)(k0 + ty * 4 + i) * N + n0 + tx];
  __syncthreads();
#pragma unroll
  for (int i = 0; i < 4; ++i)
    dst[(size_t)(n0 + ty * 4 + i) * K + k0 + tx] = f2bf(tile[tx][ty * 4 + i]);
}

__global__ void __launch_bounds__(256)
prep_kernel(const float* __restrict__ x,
            const float* __restrict__ Wqkv,
            const float* __restrict__ Wout,
            u16x8* __restrict__ xb,
            unsigned short* __restrict__ WqkvT,
            unsigned short* __restrict__ WoutT,
            float2* __restrict__ rtbl) {
  __shared__ float tile[32][33];
  const int bid = blockIdx.x, tid = threadIdx.x;
  if (bid < 2048) {                       // cast x -> bf16
    const int i = bid * 256 + tid;        // 524288 total, exact
    const float4 a = ((const float4*)x)[2 * i];
    const float4 b = ((const float4*)x)[2 * i + 1];
    u16x8 o;
    o[0] = f2bf(a.x); o[1] = f2bf(a.y); o[2] = f2bf(a.z); o[3] = f2bf(a.w);
    o[4] = f2bf(b.x); o[5] = f2bf(b.y); o[6] = f2bf(b.z); o[7] = f2bf(b.w);
    xb[i] = o;
  } else if (bid < 2304) {                // RoPE table
    const int i = (bid - 2048) * 256 + tid;   // 65536
    const int pos = i >> 5, j = i & 31;
    const float inv = exp2f(-(float)j * 0.4152410118609203f);   // log2(1e4)/32
    float s, c;
    sincosf((float)pos * inv, &s, &c);
    rtbl[i] = make_float2(c, s);
  } else if (bid < 5376) {                // Wqkv transpose
    const int t = bid - 2304;             // 96 x 32
    transpose_tile(Wqkv, WqkvT, D_, 3 * D_, (t % 96) * 32, (t / 96) * 32, tid, tile);
  } else {                                // Wout transpose
    const int t = bid - 5376;             // 32 x 32
    transpose_tile(Wout, WoutT, D_, D_, (t % 32) * 32, (t / 32) * 32, tid, tile);
  }
}

// ---------------------------------------------------------------------------
// gemm_bt4 (R19): C = A * Bt^T + bias. 128x128 tile, BK=64, 8 waves (512
// thr), 4M x 2N wave grid: wave (wr=w>>1, wc=w&1) owns 32x64 out = acc[2][4].
// Rows = 128B -> (row&7)<<4 XOR swizzle (0 conflicts). LDS 64KB -> 2
// blocks/CU -> 4 waves/SIMD. XCD n-banding grid (R18). 4 gloads/thread/iter.
// MODE 0: RoPE(Q,K)+sigma-V epilogue via per-wave 8KB LDS tile, coalesced out.
// MODE 1: fp32 out + bias.
// ---------------------------------------------------------------------------
template <int MODE>
__global__ void __launch_bounds__(512)
gemm_bt4(const unsigned short* __restrict__ A,
         const unsigned short* __restrict__ Bt,
         const float* __restrict__ bias,
         const float2* __restrict__ rt,
         float* __restrict__ outF,
         unsigned short* __restrict__ Qb,
         unsigned short* __restrict__ Kb,
         unsigned short* __restrict__ Vt,
         int M, int N, int K) {
  __shared__ unsigned short As[2][8192];   // [buf][128 rows][64 k] bf16, swz
  __shared__ unsigned short Bs[2][8192];
  const int tid = threadIdx.x;
  const int w = tid >> 6, l = tid & 63;
  const int lg = l >> 4, ll = l & 15;
  const int wr = w >> 1, wc = w & 1;       // 4M x 2N wave grid
  const int wm = wr * 32, wn = wc * 64;
  // R18: XCD n-banding (nx % 8 == 0). xcd owns n-band; m-major inside.
  const int nx = N >> 7;
  const int nband = nx >> 3;
  const int xcd = blockIdx.x & 7;
  const int bidx = blockIdx.x >> 3;
  const int n0 = (xcd * nband + bidx % nband) * 128;
  const int m0 = (bidx / nband) * 128;

  f32x4 acc[2][4] = {};

  // staging: idx = c*512 + tid -> row = idx>>3 (0..127), slot = idx&7;
  // source col pre-swizzled (slot ^ (row&7)) so linear-LDS + XOR-read works.
  int srcOff[2];
#pragma unroll
  for (int c = 0; c < 2; ++c) {
    const int sidx = c * 512 + tid;
    const int row = sidx >> 3, slot = sidx & 7;
    srcOff[c] = row * K + ((slot ^ (row & 7)) << 3);   // ushort offset
  }
  const unsigned short* gA = A + (size_t)m0 * K;
  const unsigned short* gB = Bt + (size_t)n0 * K;

  auto stage = [&](int bsel, int kt) {
    const int kk = kt * 64;
#pragma unroll
    for (int c = 0; c < 2; ++c)
      gload_lds16(gA + srcOff[c] + kk, &As[bsel][c * 4096 + w * 512]);
#pragma unroll
    for (int c = 0; c < 2; ++c)
      gload_lds16(gB + srcOff[c] + kk, &Bs[bsel][c * 4096 + w * 512]);
  };

  const int NT = K >> 6;                   // 16
  int buf = 0;

  stage(0, 0);
  for (int kt = 0; kt < NT; ++kt) {
    __syncthreads();                      // drains vmcnt -> staged tile visible
    if (kt + 1 < NT) stage(buf ^ 1, kt + 1);
    const char* pa = (const char*)&As[buf][0];
    const char* pb = (const char*)&Bs[buf][0];
#pragma unroll
    for (int kk = 0; kk < 2; ++kk) {
      bf16x8 af[2], bfv[4];
#pragma unroll
      for (int mi = 0; mi < 2; ++mi) {
        const int row = wm + mi * 16 + ll;
        af[mi] = *(const bf16x8*)(pa + row * 128 +
                                  ((kk * 64 + lg * 16) ^ ((row & 7) << 4)));
      }
#pragma unroll
      for (int ni = 0; ni < 4; ++ni) {
        const int row = wn + ni * 16 + ll;
        bfv[ni] = *(const bf16x8*)(pb + row * 128 +
                                   ((kk * 64 + lg * 16) ^ ((row & 7) << 4)));
      }
      __builtin_amdgcn_s_setprio(1);
#pragma unroll
      for (int mi = 0; mi < 2; ++mi)
#pragma unroll
        for (int ni = 0; ni < 4; ++ni)
          acc[mi][ni] = __builtin_amdgcn_mfma_f32_16x16x32_bf16(
              af[mi], bfv[ni], acc[mi][ni], 0, 0, 0);
      __builtin_amdgcn_s_setprio(0);
    }
    buf ^= 1;
  }

  // epilogue. C layout: row = (l>>4)*4 + reg, col = l&15   (guide m89/m91)
  if (MODE == 0) {
    __syncthreads();                      // all waves done reading As/Bs
    // per-wave staging tile: 8KB (4096 u16). Q/K: [32 rows][72]; V: [64 d][40]
    unsigned short* et = (w < 4 ? &As[0][0] : &Bs[0][0]) + (w & 3) * 4096;
    const int t  = (n0 + wn) >> 10;       // 0=q 1=k 2=v, wave-uniform
    const int bb = (m0 + wm) >> 11;       // batch (wave-uniform; 32 | 2048)
    const int P0 = (m0 + wm) & 2047;      // 32-aligned pos window base
    const int h  = ((n0 + wn) & 1023) >> 6;
    const int bh = bb * H_ + h;
    if (t == 2) {                         // V: sigma at LDS-write, et[d][posS]
#pragma unroll
      for (int ni = 0; ni < 4; ++ni) {
        const int d = ni * 16 + ll;
        const float bv = bias[n0 + wn + ni * 16 + ll];
#pragma unroll
        for (int mi = 0; mi < 2; ++mi) {
          const int row0 = mi * 16 + lg * 4;        // local pos in [0,32)
          const int wb = (row0 >> 2) & 7;
          const int posS = 8 * (wb & 3) + 4 * (wb >> 2);
#pragma unroll
          for (int rg = 0; rg < 4; ++rg)
            et[d * 40 + posS + rg] = f2bf(acc[mi][ni][rg] + bv);
        }
      }
      // coalesced out: 4 passes of 16 d-rows x 4 slots (16B)
      unsigned short* gbase = Vt + (size_t)bh * HD_ * L_ + P0;
#pragma unroll
      for (int pass = 0; pass < 4; ++pass) {
        const int d = pass * 16 + (l >> 2);
        const int slot = l & 3;
        const u16x8 v = *(const u16x8*)(et + d * 40 + slot * 8);
        *(u16x8*)(gbase + (size_t)d * L_ + slot * 8) = v;
      }
    } else {                              // Q/K: RoPE in-register -> et[row][d]
      unsigned short* dst = (t == 0) ? Qb : Kb;
      const float qsc = (t == 0) ? QSC : 1.0f;
#pragma unroll
      for (int ni = 0; ni < 2; ++ni) {
        const int d = ni * 16 + ll;       // 0..31
        const float bv1 = bias[n0 + wn + ni * 16 + ll];
        const float bv2 = bias[n0 + wn + (ni + 2) * 16 + ll];
#pragma unroll
        for (int mi = 0; mi < 2; ++mi) {
#pragma unroll
          for (int rg = 0; rg < 4; ++rg) {
            const int row = mi * 16 + lg * 4 + rg;  // local pos in [0,32)
            const float2 cs = rt[(P0 + row) * 32 + d];
            const float q1 = acc[mi][ni][rg] + bv1;
            const float q2 = acc[mi][ni + 2][rg] + bv2;
            et[row * 72 + d]      = f2bf((q1 * cs.x - q2 * cs.y) * qsc);
            et[row * 72 + d + 32] = f2bf((q2 * cs.x + q1 * cs.y) * qsc);
          }
        }
      }
      // coalesced out: 4 passes of 8 rows x 8 slots (16B) = 1KB contiguous
      unsigned short* gbase = dst + ((size_t)bh * L_ + P0) * HD_;
#pragma unroll
      for (int pass = 0; pass < 4; ++pass) {
        const int row = pass * 8 + (l >> 3);
        const int slot = l & 7;
        const u16x8 v = *(const u16x8*)(et + row * 72 + slot * 8);
        *(u16x8*)(gbase + (size_t)row * HD_ + slot * 8) = v;
      }
    }
  } else {
#pragma unroll
    for (int ni = 0; ni < 4; ++ni) {
      const int n = n0 + wn + ni * 16 + ll;
      const float bv = bias[n];
#pragma unroll
      for (int mi = 0; mi < 2; ++mi) {
        const int row0 = m0 + wm + mi * 16 + lg * 4;
#pragma unroll
        for (int rg = 0; rg < 4; ++rg)
          outF[(size_t)(row0 + rg) * N + n] = acc[mi][ni][rg] + bv;
      }
    }
  }
}

// ---------------------------------------------------------------------------
// Flash attention (R13, frozen): 8 waves x 16 q-rows; KVBLK=128 as 2x[64][64]
// chunks; swapped QK^T; in-register P; sigma-permuted Vt; no-max softmax;
// raw v_exp_f32; row sum via osum = mfma(pa, ones).
// ---------------------------------------------------------------------------
__global__ void __launch_bounds__(512)
attn_kernel(const unsigned short* __restrict__ Qb,
            const unsigned short* __restrict__ Kb,
            const unsigned short* __restrict__ Vt,
            unsigned short* __restrict__ Ob) {
  __shared__ unsigned short Ks[2][2][4096];  // [buf][kc][kv 64][d 64], swizzled
  __shared__ unsigned short Vs[2][2][4096];  // [buf][kc][d 64][kv' 64], swizzled
  const int tid = threadIdx.x, w = tid >> 6, l = tid & 63;
  const int lg = l >> 4, ll = l & 15;
  const int bid = ((blockIdx.x & 7) << 6) + (blockIdx.x >> 3);
  const int bh  = bid >> 4;
  const int q0  = (bid & 15) * 128;
  const unsigned short* Qp = Qb + ((size_t)bh * L_ + q0 + w * 16) * HD_;
  const unsigned short* Kp = Kb + (size_t)bh * L_ * HD_;
  const unsigned short* Vp = Vt + (size_t)bh * HD_ * L_;

  const int srow = tid >> 3;
  const int scol = ((tid & 7) ^ (srow & 7)) * 8;
  auto stage = [&](int bsel, int kv0) {
#pragma unroll
    for (int c = 0; c < 2; ++c) {
      gload_lds16(Kp + (size_t)(kv0 + c * 64 + srow) * HD_ + scol, &Ks[bsel][c][w * 512]);
      gload_lds16(Vp + (size_t)srow * L_ + kv0 + c * 64 + scol, &Vs[bsel][c][w * 512]);
    }
  };

  bf16x8 qf[2];
#pragma unroll
  for (int ks = 0; ks < 2; ++ks)
    qf[ks] = *(const bf16x8*)(Qp + (size_t)ll * HD_ + ks * 32 + 8 * lg);

  bf16x8 ones;
#pragma unroll
  for (int j = 0; j < 8; ++j) ones[j] = (short)0x3F80;

  f32x4 o[4] = {};
  f32x4 osum = {};                           // row-sum acc: osum[rg] for q=lg*4+rg

  stage(0, 0);
  __syncthreads();

  int buf = 0;
  for (int t = 0; t < 16; ++t) {
    if (t + 1 < 16) stage(buf ^ 1, (t + 1) * 128);
    f32x4 s[2][4];

#pragma unroll
    for (int kc = 0; kc < 2; ++kc) {
      const char* Ksb = (const char*)&Ks[buf][kc][0];
      bf16x8 kfr[4][2];
#pragma unroll
      for (int ni = 0; ni < 4; ++ni)
#pragma unroll
        for (int ks = 0; ks < 2; ++ks)
          kfr[ni][ks] = *(const bf16x8*)(Ksb + (ni * 16 + ll) * 128 +
                                         ((ks * 64 + lg * 16) ^ ((ll & 7) << 4)));
#pragma unroll
      for (int ni = 0; ni < 4; ++ni) s[kc][ni] = f32x4{0.f, 0.f, 0.f, 0.f};
      __builtin_amdgcn_s_setprio(1);
#pragma unroll
      for (int ks = 0; ks < 2; ++ks)
#pragma unroll
        for (int ni = 0; ni < 4; ++ni)
          s[kc][ni] = __builtin_amdgcn_mfma_f32_16x16x32_bf16(kfr[ni][ks], qf[ks], s[kc][ni], 0, 0, 0);
      __builtin_amdgcn_s_setprio(0);
    }

    bf16x8 pa[2][2];                       // [kc][ks]
#pragma unroll
    for (int kc = 0; kc < 2; ++kc) {
      uint32_t wd[4][2];
#pragma unroll
      for (int ni = 0; ni < 4; ++ni) {
        const float p0 = fast_exp2(s[kc][ni][0]);
        const float p1 = fast_exp2(s[kc][ni][1]);
        const float p2 = fast_exp2(s[kc][ni][2]);
        const float p3 = fast_exp2(s[kc][ni][3]);
        wd[ni][0] = cvtpk_bf16(p0, p1);
        wd[ni][1] = cvtpk_bf16(p2, p3);
      }
#pragma unroll
      for (int ks = 0; ks < 2; ++ks) {
        union { uint32_t u[4]; bf16x8 v; } pu;
        pu.u[0] = wd[2 * ks][0];     pu.u[1] = wd[2 * ks][1];
        pu.u[2] = wd[2 * ks + 1][0]; pu.u[3] = wd[2 * ks + 1][1];
        pa[kc][ks] = pu.v;
      }
    }

#pragma unroll
    for (int kc = 0; kc < 2; ++kc) {
      const char* Vsb = (const char*)&Vs[buf][kc][0];
      bf16x8 vf[2][4];
#pragma unroll
      for (int ks = 0; ks < 2; ++ks)
#pragma unroll
        for (int ni = 0; ni < 4; ++ni)
          vf[ks][ni] = *(const bf16x8*)(Vsb + (ni * 16 + ll) * 128 +
                                        ((ks * 64 + lg * 16) ^ ((ll & 7) << 4)));
      __builtin_amdgcn_s_setprio(1);
#pragma unroll
      for (int ks = 0; ks < 2; ++ks) {
#pragma unroll
        for (int ni = 0; ni < 4; ++ni)
          o[ni] = __builtin_amdgcn_mfma_f32_16x16x32_bf16(pa[kc][ks], vf[ks][ni], o[ni], 0, 0, 0);
        osum = __builtin_amdgcn_mfma_f32_16x16x32_bf16(pa[kc][ks], ones, osum, 0, 0, 0);
      }
      __builtin_amdgcn_s_setprio(0);
    }

    __syncthreads();
    buf ^= 1;
  }

  const int b = bh >> 4, h = bh & 15;
  unsigned short* Op = Ob + ((size_t)b * L_ + q0 + w * 16) * D_ + h * HD_;
#pragma unroll
  for (int rg = 0; rg < 4; ++rg) {
    const float iq = 1.0f / osum[rg];
#pragma unroll
    for (int ni = 0; ni < 4; ++ni)
      Op[(size_t)(lg * 4 + rg) * D_ + ni * 16 + ll] = f2bf(o[ni][rg] * iq);
  }
}

// ---------------------------------------------------------------------------
extern "C" void kernel_launch(void* const* d_in, const int* in_sizes, int n_in,
                              void* d_out, int out_size, void* d_ws, size_t ws_size,
                              hipStream_t stream) {
  const float* x    = (const float*)d_in[0];
  const float* Wqkv = (const float*)d_in[1];
  const float* bqkv = (const float*)d_in[2];
  const float* Wout = (const float*)d_in[3];
  const float* bout = (const float*)d_in[4];
  float* out = (float*)d_out;

  char* ws = (char*)d_ws;                       // 48 MiB used
  unsigned short* xb    = (unsigned short*)(ws);                    // 8 MiB
  unsigned short* WqkvT = (unsigned short*)(ws + (8ull  << 20));    // 6 MiB
  unsigned short* WoutT = (unsigned short*)(ws + (14ull << 20));    // 2 MiB
  unsigned short* Qb    = (unsigned short*)(ws + (16ull << 20));    // 8 MiB
  unsigned short* Kb    = (unsigned short*)(ws + (24ull << 20));    // 8 MiB
  unsigned short* Vt    = (unsigned short*)(ws + (32ull << 20));    // 8 MiB
  unsigned short* Ob    = (unsigned short*)(ws + (40ull << 20));    // 8 MiB
  float2* rtbl = (float2*)(ws + (40ull << 20));  // aliases Ob (dead by attn)

  prep_kernel<<<6400, 256, 0, stream>>>(x, Wqkv, Wout, (u16x8*)xb, WqkvT, WoutT, rtbl);

  gemm_bt4<0><<<(3 * D_ / 128) * (BL_ / 128), 512, 0, stream>>>(
      xb, WqkvT, bqkv, rtbl, nullptr, Qb, Kb, Vt, BL_, 3 * D_, D_);

  attn_kernel<<<B_ * H_ * (L_ / 128), 512, 0, stream>>>(Qb, Kb, Vt, Ob);

  gemm_bt4<1><<<(D_ / 128) * (BL_ / 128), 512, 0, stream>>>(
      Ob, WoutT, bout, nullptr, out, nullptr, nullptr, nullptr, BL_, D_, D_);
}

// Round 20
// 106.487 us; speedup vs baseline: 1.0543x; 1.0046x over previous
//
#include <hip/hip_runtime.h>
#include <stdint.h>
#include <stddef.h>

// ---------------------------------------------------------------------------
// Fused transformer attention block for MI355X (gfx950)
//   x[2,2048,1024] fp32 -> QKV proj(+RoPE fused) -> 16-head softmax attn -> out proj
// bf16 MFMA (16x16x32), fp32 accumulate.
// R20: GEMMs -> m97-exact minimum-LDS config: BK=32, LINEAR LDS (no swizzle;
//      m97 ran 912 TF with this exact read pattern), 32KB/block -> 3 blocks/CU
//      fully resident (24 waves/CU, 1.5x R19). 8 waves 4Mx2N (R19 epilogue,
//      pitches shrunk to fit). R19 measured occupancy 27% at 64KB LDS =>
//      residency was still the throttle. attn (R13) and prep frozen.
// ---------------------------------------------------------------------------

typedef short          bf16x8 __attribute__((ext_vector_type(8)));
typedef float          f32x4  __attribute__((ext_vector_type(4)));
typedef unsigned short u16x4  __attribute__((ext_vector_type(4)));
typedef unsigned short u16x8  __attribute__((ext_vector_type(8)));

#define B_   2
#define L_   2048
#define D_   1024
#define H_   16
#define HD_  64
#define BL_  4096           // B_*L_
#define LOG2E 1.4426950408889634f
#define QSC  0.18033688011112042f   // 0.125 * LOG2E (scale+log2e folded into Q)

__device__ __forceinline__ unsigned short f2bf(float f) {   // RNE f32->bf16
  unsigned int u = __float_as_uint(f);
  u += 0x7FFFu + ((u >> 16) & 1u);
  return (unsigned short)(u >> 16);
}
__device__ __forceinline__ float bf2f(unsigned short h) {
  return __uint_as_float(((unsigned int)h) << 16);
}
__device__ __forceinline__ uint32_t cvtpk_bf16(float lo, float hi) {
  uint32_t r;
  asm("v_cvt_pk_bf16_f32 %0, %1, %2" : "=v"(r) : "v"(lo), "v"(hi));
  return r;
}
// raw v_exp_f32: D = 2^S0 (~1 ulp; inputs here are |x| < ~40, no edge cases)
__device__ __forceinline__ float fast_exp2(float x) {
  float r;
  asm("v_exp_f32 %0, %1" : "=v"(r) : "v"(x));
  return r;
}

// async global->LDS, 16B per lane; LDS dest is wave-uniform base + lane*16
__device__ __forceinline__ void gload_lds16(const unsigned short* g, unsigned short* l) {
  __builtin_amdgcn_global_load_lds(
      (__attribute__((address_space(1))) void*)g,
      (__attribute__((address_space(3))) void*)l, 16, 0, 0);
}

// ---------------------------------------------------------------------------
// Fused preprocessing (frozen): one kernel, range-partitioned grid.
// ---------------------------------------------------------------------------
__device__ __forceinline__ void transpose_tile(
    const float* __restrict__ src, unsigned short* __restrict__ dst,
    int K, int N, int n0, int k0, int tid, float (*tile)[33]) {
  const int tx = tid & 31, ty = tid >> 5;   // (32,8)
#pragma unroll
  for (int i = 0; i < 4; ++i)
    tile[ty * 4 + i][tx] = src[(size_t)(k0 + ty * 4 + i) * N + n0 + tx];
  __syncthreads();
#pragma unroll
  for (int i = 0; i < 4; ++i)
    dst[(size_t)(n0 + ty * 4 + i) * K + k0 + tx] = f2bf(tile[tx][ty * 4 + i]);
}

__global__ void __launch_bounds__(256)
prep_kernel(const float* __restrict__ x,
            const float* __restrict__ Wqkv,
            const float* __restrict__ Wout,
            u16x8* __restrict__ xb,
            unsigned short* __restrict__ WqkvT,
            unsigned short* __restrict__ WoutT,
            float2* __restrict__ rtbl) {
  __shared__ float tile[32][33];
  const int bid = blockIdx.x, tid = threadIdx.x;
  if (bid < 2048) {                       // cast x -> bf16
    const int i = bid * 256 + tid;        // 524288 total, exact
    const float4 a = ((const float4*)x)[2 * i];
    const float4 b = ((const float4*)x)[2 * i + 1];
    u16x8 o;
    o[0] = f2bf(a.x); o[1] = f2bf(a.y); o[2] = f2bf(a.z); o[3] = f2bf(a.w);
    o[4] = f2bf(b.x); o[5] = f2bf(b.y); o[6] = f2bf(b.z); o[7] = f2bf(b.w);
    xb[i] = o;
  } else if (bid < 2304) {                // RoPE table
    const int i = (bid - 2048) * 256 + tid;   // 65536
    const int pos = i >> 5, j = i & 31;
    const float inv = exp2f(-(float)j * 0.4152410118609203f);   // log2(1e4)/32
    float s, c;
    sincosf((float)pos * inv, &s, &c);
    rtbl[i] = make_float2(c, s);
  } else if (bid < 5376) {                // Wqkv transpose
    const int t = bid - 2304;             // 96 x 32
    transpose_tile(Wqkv, WqkvT, D_, 3 * D_, (t % 96) * 32, (t / 96) * 32, tid, tile);
  } else {                                // Wout transpose
    const int t = bid - 5376;             // 32 x 32
    transpose_tile(Wout, WoutT, D_, D_, (t % 32) * 32, (t / 32) * 32, tid, tile);
  }
}

// ---------------------------------------------------------------------------
// gemm_bt5 (R20): C = A * Bt^T + bias. 128x128 tile, BK=32, 8 waves (512
// thr), 4M x 2N wave grid: wave (wr, wc) owns 32x64 out = acc[2][4].
// LINEAR LDS (m97-exact): As/Bs [buf][128 rows][32 k] bf16, 32KB total ->
// 3 blocks/CU resident. 1 gload/thread/operand/iter; 32 K-iters.
// XCD n-banding grid (R18). MODE 0: RoPE(Q,K)+sigma-V epilogue via per-wave
// 4KB LDS tile (Q/K pitch 64, V pitch 32), coalesced u16x8 out. MODE 1: fp32.
// ---------------------------------------------------------------------------
template <int MODE>
__global__ void __launch_bounds__(512)
gemm_bt5(const unsigned short* __restrict__ A,
         const unsigned short* __restrict__ Bt,
         const float* __restrict__ bias,
         const float2* __restrict__ rt,
         float* __restrict__ outF,
         unsigned short* __restrict__ Qb,
         unsigned short* __restrict__ Kb,
         unsigned short* __restrict__ Vt,
         int M, int N, int K) {
  __shared__ unsigned short As[2][4096];   // [buf][128 rows][32 k] bf16, linear
  __shared__ unsigned short Bs[2][4096];
  const int tid = threadIdx.x;
  const int w = tid >> 6, l = tid & 63;
  const int lg = l >> 4, ll = l & 15;
  const int wr = w >> 1, wc = w & 1;       // 4M x 2N wave grid
  const int wm = wr * 32, wn = wc * 64;
  // R18: XCD n-banding (nx % 8 == 0). xcd owns n-band; m-major inside.
  const int nx = N >> 7;
  const int nband = nx >> 3;
  const int xcd = blockIdx.x & 7;
  const int bidx = blockIdx.x >> 3;
  const int n0 = (xcd * nband + bidx % nband) * 128;
  const int m0 = (bidx / nband) * 128;

  f32x4 acc[2][4] = {};

  // staging (linear, m97-exact): thread -> row = tid>>2, slot = tid&3.
  const int srow = tid >> 2, sslot = tid & 3;
  const int srcOff = srow * K + sslot * 8;           // ushort offset
  const unsigned short* gA = A + (size_t)m0 * K;
  const unsigned short* gB = Bt + (size_t)n0 * K;

  auto stage = [&](int bsel, int kt) {
    const int kk = kt * 32;
    gload_lds16(gA + srcOff + kk, &As[bsel][w * 512]);
    gload_lds16(gB + srcOff + kk, &Bs[bsel][w * 512]);
  };

  const int NT = K >> 5;                   // 32
  int buf = 0;

  stage(0, 0);
  for (int kt = 0; kt < NT; ++kt) {
    __syncthreads();                      // drains vmcnt -> staged tile visible
    if (kt + 1 < NT) stage(buf ^ 1, kt + 1);
    const char* pa = (const char*)&As[buf][0];
    const char* pb = (const char*)&Bs[buf][0];
    bf16x8 af[2], bfv[4];
#pragma unroll
    for (int mi = 0; mi < 2; ++mi) {
      const int row = wm + mi * 16 + ll;
      af[mi] = *(const bf16x8*)(pa + row * 64 + lg * 16);
    }
#pragma unroll
    for (int ni = 0; ni < 4; ++ni) {
      const int row = wn + ni * 16 + ll;
      bfv[ni] = *(const bf16x8*)(pb + row * 64 + lg * 16);
    }
    __builtin_amdgcn_s_setprio(1);
#pragma unroll
    for (int mi = 0; mi < 2; ++mi)
#pragma unroll
      for (int ni = 0; ni < 4; ++ni)
        acc[mi][ni] = __builtin_amdgcn_mfma_f32_16x16x32_bf16(
            af[mi], bfv[ni], acc[mi][ni], 0, 0, 0);
    __builtin_amdgcn_s_setprio(0);
    buf ^= 1;
  }

  // epilogue. C layout: row = (l>>4)*4 + reg, col = l&15   (guide m89/m91)
  if (MODE == 0) {
    __syncthreads();                      // all waves done reading As/Bs
    // per-wave staging tile: 2048 u16 = 4KB. Q/K: [32 rows][64]; V: [64 d][32]
    unsigned short* et = (w < 4 ? &As[0][0] : &Bs[0][0]) + (w & 3) * 2048;
    const int t  = (n0 + wn) >> 10;       // 0=q 1=k 2=v, wave-uniform
    const int bb = (m0 + wm) >> 11;       // batch (wave-uniform; 32 | 2048)
    const int P0 = (m0 + wm) & 2047;      // 32-aligned pos window base
    const int h  = ((n0 + wn) & 1023) >> 6;
    const int bh = bb * H_ + h;
    if (t == 2) {                         // V: sigma at LDS-write, et[d][posS]
#pragma unroll
      for (int ni = 0; ni < 4; ++ni) {
        const int d = ni * 16 + ll;
        const float bv = bias[n0 + wn + ni * 16 + ll];
#pragma unroll
        for (int mi = 0; mi < 2; ++mi) {
          const int row0 = mi * 16 + lg * 4;        // local pos in [0,32)
          const int wb = (row0 >> 2) & 7;
          const int posS = 8 * (wb & 3) + 4 * (wb >> 2);
#pragma unroll
          for (int rg = 0; rg < 4; ++rg)
            et[d * 32 + posS + rg] = f2bf(acc[mi][ni][rg] + bv);
        }
      }
      // coalesced out: 4 passes of 16 d-rows x 4 slots (16B)
      unsigned short* gbase = Vt + (size_t)bh * HD_ * L_ + P0;
#pragma unroll
      for (int pass = 0; pass < 4; ++pass) {
        const int d = pass * 16 + (l >> 2);
        const int slot = l & 3;
        const u16x8 v = *(const u16x8*)(et + d * 32 + slot * 8);
        *(u16x8*)(gbase + (size_t)d * L_ + slot * 8) = v;
      }
    } else {                              // Q/K: RoPE in-register -> et[row][d]
      unsigned short* dst = (t == 0) ? Qb : Kb;
      const float qsc = (t == 0) ? QSC : 1.0f;
#pragma unroll
      for (int ni = 0; ni < 2; ++ni) {
        const int d = ni * 16 + ll;       // 0..31
        const float bv1 = bias[n0 + wn + ni * 16 + ll];
        const float bv2 = bias[n0 + wn + (ni + 2) * 16 + ll];
#pragma unroll
        for (int mi = 0; mi < 2; ++mi) {
#pragma unroll
          for (int rg = 0; rg < 4; ++rg) {
            const int row = mi * 16 + lg * 4 + rg;  // local pos in [0,32)
            const float2 cs = rt[(P0 + row) * 32 + d];
            const float q1 = acc[mi][ni][rg] + bv1;
            const float q2 = acc[mi][ni + 2][rg] + bv2;
            et[row * 64 + d]      = f2bf((q1 * cs.x - q2 * cs.y) * qsc);
            et[row * 64 + d + 32] = f2bf((q2 * cs.x + q1 * cs.y) * qsc);
          }
        }
      }
      // coalesced out: 4 passes of 8 rows x 8 slots (16B) = 1KB contiguous
      unsigned short* gbase = dst + ((size_t)bh * L_ + P0) * HD_;
#pragma unroll
      for (int pass = 0; pass < 4; ++pass) {
        const int row = pass * 8 + (l >> 3);
        const int slot = l & 7;
        const u16x8 v = *(const u16x8*)(et + row * 64 + slot * 8);
        *(u16x8*)(gbase + (size_t)row * HD_ + slot * 8) = v;
      }
    }
  } else {
#pragma unroll
    for (int ni = 0; ni < 4; ++ni) {
      const int n = n0 + wn + ni * 16 + ll;
      const float bv = bias[n];
#pragma unroll
      for (int mi = 0; mi < 2; ++mi) {
        const int row0 = m0 + wm + mi * 16 + lg * 4;
#pragma unroll
        for (int rg = 0; rg < 4; ++rg)
          outF[(size_t)(row0 + rg) * N + n] = acc[mi][ni][rg] + bv;
      }
    }
  }
}

// ---------------------------------------------------------------------------
// Flash attention (R13, frozen): 8 waves x 16 q-rows; KVBLK=128 as 2x[64][64]
// chunks; swapped QK^T; in-register P; sigma-permuted Vt; no-max softmax;
// raw v_exp_f32; row sum via osum = mfma(pa, ones).
// ---------------------------------------------------------------------------
__global__ void __launch_bounds__(512)
attn_kernel(const unsigned short* __restrict__ Qb,
            const unsigned short* __restrict__ Kb,
            const unsigned short* __restrict__ Vt,
            unsigned short* __restrict__ Ob) {
  __shared__ unsigned short Ks[2][2][4096];  // [buf][kc][kv 64][d 64], swizzled
  __shared__ unsigned short Vs[2][2][4096];  // [buf][kc][d 64][kv' 64], swizzled
  const int tid = threadIdx.x, w = tid >> 6, l = tid & 63;
  const int lg = l >> 4, ll = l & 15;
  const int bid = ((blockIdx.x & 7) << 6) + (blockIdx.x >> 3);
  const int bh  = bid >> 4;
  const int q0  = (bid & 15) * 128;
  const unsigned short* Qp = Qb + ((size_t)bh * L_ + q0 + w * 16) * HD_;
  const unsigned short* Kp = Kb + (size_t)bh * L_ * HD_;
  const unsigned short* Vp = Vt + (size_t)bh * HD_ * L_;

  const int srow = tid >> 3;
  const int scol = ((tid & 7) ^ (srow & 7)) * 8;
  auto stage = [&](int bsel, int kv0) {
#pragma unroll
    for (int c = 0; c < 2; ++c) {
      gload_lds16(Kp + (size_t)(kv0 + c * 64 + srow) * HD_ + scol, &Ks[bsel][c][w * 512]);
      gload_lds16(Vp + (size_t)srow * L_ + kv0 + c * 64 + scol, &Vs[bsel][c][w * 512]);
    }
  };

  bf16x8 qf[2];
#pragma unroll
  for (int ks = 0; ks < 2; ++ks)
    qf[ks] = *(const bf16x8*)(Qp + (size_t)ll * HD_ + ks * 32 + 8 * lg);

  bf16x8 ones;
#pragma unroll
  for (int j = 0; j < 8; ++j) ones[j] = (short)0x3F80;

  f32x4 o[4] = {};
  f32x4 osum = {};                           // row-sum acc: osum[rg] for q=lg*4+rg

  stage(0, 0);
  __syncthreads();

  int buf = 0;
  for (int t = 0; t < 16; ++t) {
    if (t + 1 < 16) stage(buf ^ 1, (t + 1) * 128);
    f32x4 s[2][4];

#pragma unroll
    for (int kc = 0; kc < 2; ++kc) {
      const char* Ksb = (const char*)&Ks[buf][kc][0];
      bf16x8 kfr[4][2];
#pragma unroll
      for (int ni = 0; ni < 4; ++ni)
#pragma unroll
        for (int ks = 0; ks < 2; ++ks)
          kfr[ni][ks] = *(const bf16x8*)(Ksb + (ni * 16 + ll) * 128 +
                                         ((ks * 64 + lg * 16) ^ ((ll & 7) << 4)));
#pragma unroll
      for (int ni = 0; ni < 4; ++ni) s[kc][ni] = f32x4{0.f, 0.f, 0.f, 0.f};
      __builtin_amdgcn_s_setprio(1);
#pragma unroll
      for (int ks = 0; ks < 2; ++ks)
#pragma unroll
        for (int ni = 0; ni < 4; ++ni)
          s[kc][ni] = __builtin_amdgcn_mfma_f32_16x16x32_bf16(kfr[ni][ks], qf[ks], s[kc][ni], 0, 0, 0);
      __builtin_amdgcn_s_setprio(0);
    }

    bf16x8 pa[2][2];                       // [kc][ks]
#pragma unroll
    for (int kc = 0; kc < 2; ++kc) {
      uint32_t wd[4][2];
#pragma unroll
      for (int ni = 0; ni < 4; ++ni) {
        const float p0 = fast_exp2(s[kc][ni][0]);
        const float p1 = fast_exp2(s[kc][ni][1]);
        const float p2 = fast_exp2(s[kc][ni][2]);
        const float p3 = fast_exp2(s[kc][ni][3]);
        wd[ni][0] = cvtpk_bf16(p0, p1);
        wd[ni][1] = cvtpk_bf16(p2, p3);
      }
#pragma unroll
      for (int ks = 0; ks < 2; ++ks) {
        union { uint32_t u[4]; bf16x8 v; } pu;
        pu.u[0] = wd[2 * ks][0];     pu.u[1] = wd[2 * ks][1];
        pu.u[2] = wd[2 * ks + 1][0]; pu.u[3] = wd[2 * ks + 1][1];
        pa[kc][ks] = pu.v;
      }
    }

#pragma unroll
    for (int kc = 0; kc < 2; ++kc) {
      const char* Vsb = (const char*)&Vs[buf][kc][0];
      bf16x8 vf[2][4];
#pragma unroll
      for (int ks = 0; ks < 2; ++ks)
#pragma unroll
        for (int ni = 0; ni < 4; ++ni)
          vf[ks][ni] = *(const bf16x8*)(Vsb + (ni * 16 + ll) * 128 +
                                        ((ks * 64 + lg * 16) ^ ((ll & 7) << 4)));
      __builtin_amdgcn_s_setprio(1);
#pragma unroll
      for (int ks = 0; ks < 2; ++ks) {
#pragma unroll
        for (int ni = 0; ni < 4; ++ni)
          o[ni] = __builtin_amdgcn_mfma_f32_16x16x32_bf16(pa[kc][ks], vf[ks][ni], o[ni], 0, 0, 0);
        osum = __builtin_amdgcn_mfma_f32_16x16x32_bf16(pa[kc][ks], ones, osum, 0, 0, 0);
      }
      __builtin_amdgcn_s_setprio(0);
    }

    __syncthreads();
    buf ^= 1;
  }

  const int b = bh >> 4, h = bh & 15;
  unsigned short* Op = Ob + ((size_t)b * L_ + q0 + w * 16) * D_ + h * HD_;
#pragma unroll
  for (int rg = 0; rg < 4; ++rg) {
    const float iq = 1.0f / osum[rg];
#pragma unroll
    for (int ni = 0; ni < 4; ++ni)
      Op[(size_t)(lg * 4 + rg) * D_ + ni * 16 + ll] = f2bf(o[ni][rg] * iq);
  }
}

// ---------------------------------------------------------------------------
extern "C" void kernel_launch(void* const* d_in, const int* in_sizes, int n_in,
                              void* d_out, int out_size, void* d_ws, size_t ws_size,
                              hipStream_t stream) {
  const float* x    = (const float*)d_in[0];
  const float* Wqkv = (const float*)d_in[1];
  const float* bqkv = (const float*)d_in[2];
  const float* Wout = (const float*)d_in[3];
  const float* bout = (const float*)d_in[4];
  float* out = (float*)d_out;

  char* ws = (char*)d_ws;                       // 48 MiB used
  unsigned short* xb    = (unsigned short*)(ws);                    // 8 MiB
  unsigned short* WqkvT = (unsigned short*)(ws + (8ull  << 20));    // 6 MiB
  unsigned short* WoutT = (unsigned short*)(ws + (14ull << 20));    // 2 MiB
  unsigned short* Qb    = (unsigned short*)(ws + (16ull << 20));    // 8 MiB
  unsigned short* Kb    = (unsigned short*)(ws + (24ull << 20));    // 8 MiB
  unsigned short* Vt    = (unsigned short*)(ws + (32ull << 20));    // 8 MiB
  unsigned short* Ob    = (unsigned short*)(ws + (40ull << 20));    // 8 MiB
  float2* rtbl = (float2*)(ws + (40ull << 20));  // aliases Ob (dead by attn)

  prep_kernel<<<6400, 256, 0, stream>>>(x, Wqkv, Wout, (u16x8*)xb, WqkvT, WoutT, rtbl);

  gemm_bt5<0><<<(3 * D_ / 128) * (BL_ / 128), 512, 0, stream>>>(
      xb, WqkvT, bqkv, rtbl, nullptr, Qb, Kb, Vt, BL_, 3 * D_, D_);

  attn_kernel<<<B_ * H_ * (L_ / 128), 512, 0, stream>>>(Qb, Kb, Vt, Ob);

  gemm_bt5<1><<<(D_ / 128) * (BL_ / 128), 512, 0, stream>>>(
      Ob, WoutT, bout, nullptr, out, nullptr, nullptr, nullptr, BL_, D_, D_);
}